// Round 3
// baseline (841.772 us; speedup 1.0000x reference)
//
#include <hip/hip_runtime.h>
#include <hip/hip_bf16.h>

#define DD 64
#define HH 8
#define CC 8
#define LL 5

// ---------------- dtype sniff ----------------
// If x (first 4096 halfwords) interpreted as bf16 contains any |v| >= 64
// (exponent field >= 134), the underlying data must be float32 (low mantissa
// halves are ~uniform random bits). Genuine bf16 N(0,1) data never trips this.
__global__ void sniff_k(const unsigned short* __restrict__ xb, int* __restrict__ flag) {
    __shared__ int any;
    if (threadIdx.x == 0) any = 0;
    __syncthreads();
    int bad = 0;
    for (int i = threadIdx.x; i < 4096; i += 256) {
        int e = (xb[i] >> 7) & 0xFF;
        if (e >= 134) bad = 1;   // |v| >= 64 or inf/nan
    }
    if (bad) atomicOr(&any, 1);
    __syncthreads();
    if (threadIdx.x == 0) *flag = any;  // 1 = float32 data, 0 = bf16 data
}

// convert input (either f32 or bf16, per flag) to f32
__global__ void cvt_k(const void* __restrict__ in, float* __restrict__ out, int n,
                      const int* __restrict__ flag) {
    int i = blockIdx.x * blockDim.x + threadIdx.x;
    if (i >= n) return;
    if (*flag) out[i] = ((const float*)in)[i];
    else       out[i] = (float)((const __hip_bfloat16*)in)[i];
}

// store f32 result to d_out in the correct dtype (per flag)
__global__ void store_k(const float* __restrict__ in, void* __restrict__ out, int n,
                        const int* __restrict__ flag) {
    int i = blockIdx.x * blockDim.x + threadIdx.x;
    if (i >= n) return;
    if (*flag) ((float*)out)[i] = in[i];
    else       ((__hip_bfloat16*)out)[i] = (__hip_bfloat16)in[i];
}

// ---------------- CSR build ----------------
__global__ void deg_k(const int* __restrict__ dst, int* __restrict__ deg, int e) {
    int i = blockIdx.x * blockDim.x + threadIdx.x;
    if (i < e) atomicAdd(&deg[dst[i]], 1);
}

__global__ void scan_k(const int* __restrict__ deg, int* __restrict__ offs,
                       int* __restrict__ cursor, int n) {
    __shared__ int sums[1024];
    int t = threadIdx.x;
    int chunk = (n + 1023) >> 10;
    int begin = t * chunk;
    int end = min(begin + chunk, n);
    int s = 0;
    for (int i = begin; i < end; ++i) s += deg[i];
    sums[t] = s;
    __syncthreads();
    for (int off = 1; off < 1024; off <<= 1) {
        int v = (t >= off) ? sums[t - off] : 0;
        __syncthreads();
        sums[t] += v;
        __syncthreads();
    }
    int base = (t == 0) ? 0 : sums[t - 1];
    for (int i = begin; i < end; ++i) {
        offs[i] = base;
        cursor[i] = base;
        base += deg[i];
    }
    if (t == 1023) offs[n] = sums[1023];
}

__global__ void scatter_k(const int* __restrict__ src, const int* __restrict__ dst,
                          int* __restrict__ cursor, int* __restrict__ csr, int e) {
    int i = blockIdx.x * blockDim.x + threadIdx.x;
    if (i < e) {
        int d = dst[i];
        int pos = atomicAdd(&cursor[d], 1);
        csr[pos] = src[i];
    }
}

// ---------------- GEMM: Out[n,64] = A[n,64] @ W[64,64] + bias, optional relu ----------------
__global__ void __launch_bounds__(256) gemm64_k(const float* __restrict__ A,
                                                const float* __restrict__ W,
                                                const float* __restrict__ bias,
                                                float* __restrict__ Out, int n, int relu) {
    __shared__ float Ws[64][64];
    __shared__ float As[16][64];
    int tid = threadIdx.x;
    for (int i = tid; i < 4096; i += 256) Ws[i >> 6][i & 63] = W[i];
    int rowbase = blockIdx.x * 16;
    for (int i = tid; i < 1024; i += 256) {
        int r = i >> 6, c = i & 63;
        int gr = rowbase + r;
        As[r][c] = (gr < n) ? A[gr * 64 + c] : 0.f;
    }
    __syncthreads();
    int c = tid & 63;
    int r0 = tid >> 6;  // 0..3
    float bcol = bias[c];
    for (int rr = 0; rr < 4; ++rr) {
        int r = r0 * 4 + rr;
        int gr = rowbase + r;
        if (gr >= n) break;
        float acc = 0.f;
#pragma unroll
        for (int k = 0; k < 64; ++k) acc += As[r][k] * Ws[k][c];
        acc += bcol;
        if (relu) acc = fmaxf(acc, 0.f);
        Out[gr * 64 + c] = acc;
    }
}

// ---------------- fused GAT layer ----------------
// one wave (64 lanes) per node; lane = feature index f = h*8 + c
__global__ void __launch_bounds__(256) gat_k(const float* __restrict__ hp,   // [N,64]
                                             const int* __restrict__ offs,   // [N+1]
                                             const int* __restrict__ csr,    // [E] src grouped by dst
                                             const float* __restrict__ att,  // [H,16]
                                             const float* __restrict__ ob,   // [64]
                                             const float* __restrict__ g,    // [64]
                                             const float* __restrict__ b,    // [64]
                                             float* __restrict__ hout, int n) {
    int lane = threadIdx.x & 63;
    int wave = threadIdx.x >> 6;
    int node = blockIdx.x * 4 + wave;
    if (node >= n) return;
    int h = lane >> 3, c = lane & 7;

    float a_dst = att[h * 16 + c];
    float a_src = att[h * 16 + 8 + c];

    // x_i . att_dst  (per-head, constant over edges)
    float xi = hp[node * 64 + lane];
    float p = xi * a_dst;
    p += __shfl_xor(p, 1, 64);
    p += __shfl_xor(p, 2, 64);
    p += __shfl_xor(p, 4, 64);
    float bh = p;  // all 8 lanes of head h hold the same value

    int rs = offs[node], re = offs[node + 1];
    float m = -INFINITY, s = 0.f, acc = 0.f;
    for (int base = rs; base < re; base += 64) {
        int cnt = min(64, re - base);
        int jv = (lane < cnt) ? csr[base + lane] : 0;
        for (int e = 0; e < cnt; ++e) {
            int j = __shfl(jv, e, 64);
            float xj = hp[j * 64 + lane];
            float q = xj * a_src;
            q += __shfl_xor(q, 1, 64);
            q += __shfl_xor(q, 2, 64);
            q += __shfl_xor(q, 4, 64);
            float alpha = bh + q;
            alpha = (alpha > 0.f) ? alpha : 0.2f * alpha;  // leaky_relu 0.2
            float mn = fmaxf(m, alpha);
            float corr = __expf(m - mn);   // 0 on first edge (m=-inf)
            float ea = __expf(alpha - mn);
            s = s * corr + ea;
            acc = acc * corr + xj * ea;
            m = mn;
        }
    }

    float o = acc / (s + 1e-16f) + ob[lane];
    o = (o > 0.f) ? o : expm1f(o);  // ELU

    // LayerNorm over the 64 features (whole wave)
    float sum = o;
#pragma unroll
    for (int d = 1; d < 64; d <<= 1) sum += __shfl_xor(sum, d, 64);
    float mu = sum * (1.f / 64.f);
    float dv = o - mu;
    float sq = dv * dv;
#pragma unroll
    for (int d = 1; d < 64; d <<= 1) sq += __shfl_xor(sq, d, 64);
    float var = sq * (1.f / 64.f);
    float y = dv * rsqrtf(var + 1e-5f) * g[lane] + b[lane];
    hout[node * 64 + lane] = y;
}

// fallback pool (first, non-captured call only)
static void* g_pool = nullptr;
static size_t g_pool_sz = 0;

extern "C" void kernel_launch(void* const* d_in, const int* in_sizes, int n_in,
                              void* d_out, int out_size, void* d_ws, size_t ws_size,
                              hipStream_t stream) {
    const void* x    = d_in[0];             // [N,64]   f32 or bf16
    const int* ei    = (const int*)d_in[1]; // [2,E]
    const void* W_in = d_in[2];             // [64,64]
    const void* b_in = d_in[3];             // [64]
    const void* lw   = d_in[4];             // [L,64,64]
    const void* lb   = d_in[5];             // [L,64]
    const void* att  = d_in[6];             // [L,8,16]
    const void* ob   = d_in[7];             // [L,64]
    const void* lg   = d_in[8];             // [L,64]
    const void* lbb  = d_in[9];             // [L,64]

    const int n = in_sizes[0] / DD;      // 50000
    const int e = in_sizes[1] / 2;       // 800000
    const int* src = ei;
    const int* dst = ei + e;

    // ---- workspace sizing ----
    auto align256 = [](size_t v) { return (v + 255) & ~(size_t)255; };
    size_t need = 0;
    size_t off_h    = need; need += align256((size_t)n * DD * 4);   // hbuf  f32
    size_t off_hp   = need; need += align256((size_t)n * DD * 4);   // hpbuf f32
    size_t off_deg  = need; need += align256((size_t)n * 4);
    size_t off_offs = need; need += align256((size_t)(n + 1) * 4);
    size_t off_cur  = need; need += align256((size_t)n * 4);
    size_t off_csr  = need; need += align256((size_t)e * 4);
    size_t off_wts  = need; need += align256((size_t)26560 * 4);    // converted weights
    size_t off_flag = need; need += align256(4);

    char* ws;
    if (ws_size >= need) {
        ws = (char*)d_ws;
    } else {
        if (g_pool == nullptr || g_pool_sz < need) {
            hipMalloc(&g_pool, need);   // first call only; never during capture
            g_pool_sz = need;
        }
        ws = (char*)g_pool;
    }

    float* hbuf  = (float*)(ws + off_h);
    float* hpbuf = (float*)(ws + off_hp);
    int* deg     = (int*)(ws + off_deg);
    int* offs    = (int*)(ws + off_offs);
    int* cursor  = (int*)(ws + off_cur);
    int* csr     = (int*)(ws + off_csr);
    float* wts   = (float*)(ws + off_wts);
    int* flag    = (int*)(ws + off_flag);

    // converted-weight layout (floats)
    float* wW_in = wts;            // 4096
    float* wb_in = wts + 4096;     // 64
    float* wlw   = wts + 4160;     // 5*4096 = 20480
    float* wlb   = wts + 24640;    // 320
    float* watt  = wts + 24960;    // 640
    float* wob   = wts + 25600;    // 320
    float* wlg   = wts + 25920;    // 320
    float* wlbb  = wts + 26240;    // 320

    // ---- dtype sniff + input conversion ----
    sniff_k<<<1, 256, 0, stream>>>((const unsigned short*)x, flag);
    int nelem = n * DD;
    cvt_k<<<(nelem + 255) / 256, 256, 0, stream>>>(x, hpbuf, nelem, flag);
    cvt_k<<<(4096 + 255) / 256, 256, 0, stream>>>(W_in, wW_in, 4096, flag);
    cvt_k<<<1, 64, 0, stream>>>(b_in, wb_in, 64, flag);
    cvt_k<<<(20480 + 255) / 256, 256, 0, stream>>>(lw, wlw, 20480, flag);
    cvt_k<<<2, 256, 0, stream>>>(lb, wlb, 320, flag);
    cvt_k<<<3, 256, 0, stream>>>(att, watt, 640, flag);
    cvt_k<<<2, 256, 0, stream>>>(ob, wob, 320, flag);
    cvt_k<<<2, 256, 0, stream>>>(lg, wlg, 320, flag);
    cvt_k<<<2, 256, 0, stream>>>(lbb, wlbb, 320, flag);

    // ---- CSR build ----
    hipMemsetAsync(deg, 0, (size_t)n * 4, stream);
    deg_k<<<(e + 255) / 256, 256, 0, stream>>>(dst, deg, e);
    scan_k<<<1, 1024, 0, stream>>>(deg, offs, cursor, n);
    scatter_k<<<(e + 255) / 256, 256, 0, stream>>>(src, dst, cursor, csr, e);

    // ---- input embedding: h = relu(x @ W_in + b_in) ----
    int gblocks = (n + 15) / 16;
    gemm64_k<<<gblocks, 256, 0, stream>>>(hpbuf, wW_in, wb_in, hbuf, n, 1);

    // ---- 5 GAT layers ----
    int ablocks = (n + 3) / 4;
    for (int l = 0; l < LL; ++l) {
        gemm64_k<<<gblocks, 256, 0, stream>>>(hbuf, wlw + (size_t)l * DD * DD,
                                              wlb + (size_t)l * DD, hpbuf, n, 0);
        gat_k<<<ablocks, 256, 0, stream>>>(hpbuf, offs, csr,
                                           watt + (size_t)l * HH * 2 * CC,
                                           wob + (size_t)l * DD,
                                           wlg + (size_t)l * DD,
                                           wlbb + (size_t)l * DD, hbuf, n);
    }

    // ---- store final h to d_out in the detected dtype ----
    store_k<<<(nelem + 255) / 256, 256, 0, stream>>>(hbuf, d_out, nelem, flag);
}

// Round 4
// 727.200 us; speedup vs baseline: 1.1576x; 1.1576x over previous
//
#include <hip/hip_runtime.h>
#include <hip/hip_bf16.h>

#define DD 64
#define HH 8
#define CC 8
#define LL 5

// ---------------- dtype sniff ----------------
// If x interpreted as bf16 contains any |v| >= 64 (exp field >= 134), the
// underlying data must be float32 (low mantissa halves ~ random bits).
__global__ void sniff_k(const unsigned short* __restrict__ xb, int* __restrict__ flag) {
    __shared__ int any;
    if (threadIdx.x == 0) any = 0;
    __syncthreads();
    int bad = 0;
    for (int i = threadIdx.x; i < 4096; i += 256) {
        int e = (xb[i] >> 7) & 0xFF;
        if (e >= 134) bad = 1;
    }
    if (bad) atomicOr(&any, 1);
    __syncthreads();
    if (threadIdx.x == 0) *flag = any;  // 1 = float32 data, 0 = bf16 data
}

// convert input (either f32 or bf16, per flag) to f32
__global__ void cvt_k(const void* __restrict__ in, float* __restrict__ out, int n,
                      const int* __restrict__ flag) {
    int i = blockIdx.x * blockDim.x + threadIdx.x;
    if (i >= n) return;
    if (*flag) out[i] = ((const float*)in)[i];
    else       out[i] = (float)((const __hip_bfloat16*)in)[i];
}

// all small weight tensors in one launch -> contiguous f32 block
__global__ void cvtw_k(const void* __restrict__ W_in, const void* __restrict__ b_in,
                       const void* __restrict__ lw, const void* __restrict__ lb,
                       const void* __restrict__ att, const void* __restrict__ ob,
                       const void* __restrict__ lg, const void* __restrict__ lbb,
                       float* __restrict__ wts, const int* __restrict__ flag) {
    int i = blockIdx.x * blockDim.x + threadIdx.x;
    if (i >= 26560) return;
    const void* p; int o;
    if      (i < 4096)  { p = W_in; o = i; }
    else if (i < 4160)  { p = b_in; o = i - 4096; }
    else if (i < 24640) { p = lw;   o = i - 4160; }
    else if (i < 24960) { p = lb;   o = i - 24640; }
    else if (i < 25600) { p = att;  o = i - 24960; }
    else if (i < 25920) { p = ob;   o = i - 25600; }
    else if (i < 26240) { p = lg;   o = i - 25920; }
    else                { p = lbb;  o = i - 26240; }
    wts[i] = (*flag) ? ((const float*)p)[o] : (float)((const __hip_bfloat16*)p)[o];
}

// store f32 result to d_out in the correct dtype (per flag)
__global__ void store_k(const float* __restrict__ in, void* __restrict__ out, int n,
                        const int* __restrict__ flag) {
    int i = blockIdx.x * blockDim.x + threadIdx.x;
    if (i >= n) return;
    if (*flag) ((float*)out)[i] = in[i];
    else       ((__hip_bfloat16*)out)[i] = (__hip_bfloat16)in[i];
}

// ---------------- CSR build ----------------
__global__ void deg_k(const int* __restrict__ dst, int* __restrict__ deg, int e) {
    int i = blockIdx.x * blockDim.x + threadIdx.x;
    if (i < e) atomicAdd(&deg[dst[i]], 1);
}

// 3-phase multi-block exclusive scan (replaces 111 us single-block scan)
__global__ void scanA_k(const int* __restrict__ deg, int* __restrict__ bsum, int n) {
    __shared__ int s[256];
    int i = blockIdx.x * 256 + threadIdx.x;
    s[threadIdx.x] = (i < n) ? deg[i] : 0;
    __syncthreads();
    for (int off = 128; off > 0; off >>= 1) {
        if (threadIdx.x < off) s[threadIdx.x] += s[threadIdx.x + off];
        __syncthreads();
    }
    if (threadIdx.x == 0) bsum[blockIdx.x] = s[0];
}

__global__ void scanB_k(const int* __restrict__ bsum, int* __restrict__ bbase, int nb,
                        int* __restrict__ offs, int n) {
    __shared__ int s[256];
    int t = threadIdx.x;
    s[t] = (t < nb) ? bsum[t] : 0;
    __syncthreads();
    for (int off = 1; off < 256; off <<= 1) {
        int v = (t >= off) ? s[t - off] : 0;
        __syncthreads();
        s[t] += v;
        __syncthreads();
    }
    if (t < nb) bbase[t] = (t == 0) ? 0 : s[t - 1];
    if (t == 255) offs[n] = s[255];
}

__global__ void scanC_k(const int* __restrict__ deg, const int* __restrict__ bbase,
                        int* __restrict__ offs, int* __restrict__ cursor, int n) {
    __shared__ int s[256];
    int t = threadIdx.x;
    int i = blockIdx.x * 256 + t;
    int v = (i < n) ? deg[i] : 0;
    s[t] = v;
    __syncthreads();
    for (int off = 1; off < 256; off <<= 1) {
        int u = (t >= off) ? s[t - off] : 0;
        __syncthreads();
        s[t] += u;
        __syncthreads();
    }
    if (i < n) {
        int excl = s[t] - v + bbase[blockIdx.x];
        offs[i] = excl;
        cursor[i] = excl;
    }
}

__global__ void scatter_k(const int* __restrict__ src, const int* __restrict__ dst,
                          int* __restrict__ cursor, int* __restrict__ csr, int e) {
    int i = blockIdx.x * blockDim.x + threadIdx.x;
    if (i < e) {
        int d = dst[i];
        int pos = atomicAdd(&cursor[d], 1);
        csr[pos] = src[i];
    }
}

// ---------------- GEMM: Out[n,64] = A[n,64] @ W[64,64] + bias, optional relu ----------------
__global__ void __launch_bounds__(256) gemm64_k(const float* __restrict__ A,
                                                const float* __restrict__ W,
                                                const float* __restrict__ bias,
                                                float* __restrict__ Out, int n, int relu) {
    __shared__ float Ws[64][64];
    __shared__ float As[16][64];
    int tid = threadIdx.x;
    for (int i = tid; i < 4096; i += 256) Ws[i >> 6][i & 63] = W[i];
    int rowbase = blockIdx.x * 16;
    for (int i = tid; i < 1024; i += 256) {
        int r = i >> 6, c = i & 63;
        int gr = rowbase + r;
        As[r][c] = (gr < n) ? A[gr * 64 + c] : 0.f;
    }
    __syncthreads();
    int c = tid & 63;
    int r0 = tid >> 6;  // 0..3
    float bcol = bias[c];
    for (int rr = 0; rr < 4; ++rr) {
        int r = r0 * 4 + rr;
        int gr = rowbase + r;
        if (gr >= n) break;
        float acc = 0.f;
#pragma unroll
        for (int k = 0; k < 64; ++k) acc += As[r][k] * Ws[k][c];
        acc += bcol;
        if (relu) acc = fmaxf(acc, 0.f);
        Out[gr * 64 + c] = acc;
    }
}

// ---------------- fused GAT layer ----------------
// one wave (64 lanes) per node; lane = feature index f = h*8 + c
__global__ void __launch_bounds__(256) gat_k(const float* __restrict__ hp,   // [N,64]
                                             const int* __restrict__ offs,   // [N+1]
                                             const int* __restrict__ csr,    // [E] src grouped by dst
                                             const float* __restrict__ att,  // [H,16]
                                             const float* __restrict__ ob,   // [64]
                                             const float* __restrict__ g,    // [64]
                                             const float* __restrict__ b,    // [64]
                                             float* __restrict__ hout, int n) {
    int lane = threadIdx.x & 63;
    int wave = threadIdx.x >> 6;
    int node = blockIdx.x * 4 + wave;
    if (node >= n) return;
    int h = lane >> 3, c = lane & 7;

    float a_dst = att[h * 16 + c];
    float a_src = att[h * 16 + 8 + c];

    float xi = hp[node * 64 + lane];
    float p = xi * a_dst;
    p += __shfl_xor(p, 1, 64);
    p += __shfl_xor(p, 2, 64);
    p += __shfl_xor(p, 4, 64);
    float bh = p;  // all 8 lanes of head h hold the same value

    int rs = offs[node], re = offs[node + 1];
    float m = -INFINITY, s = 0.f, acc = 0.f;
    for (int base = rs; base < re; base += 64) {
        int cnt = min(64, re - base);
        int jv = (lane < cnt) ? csr[base + lane] : 0;
        for (int e = 0; e < cnt; ++e) {
            int j = __shfl(jv, e, 64);
            float xj = hp[j * 64 + lane];
            float q = xj * a_src;
            q += __shfl_xor(q, 1, 64);
            q += __shfl_xor(q, 2, 64);
            q += __shfl_xor(q, 4, 64);
            float alpha = bh + q;
            alpha = (alpha > 0.f) ? alpha : 0.2f * alpha;  // leaky_relu 0.2
            float mn = fmaxf(m, alpha);
            float corr = __expf(m - mn);
            float ea = __expf(alpha - mn);
            s = s * corr + ea;
            acc = acc * corr + xj * ea;
            m = mn;
        }
    }

    float o = acc / (s + 1e-16f) + ob[lane];
    o = (o > 0.f) ? o : expm1f(o);  // ELU

    float sum = o;
#pragma unroll
    for (int d = 1; d < 64; d <<= 1) sum += __shfl_xor(sum, d, 64);
    float mu = sum * (1.f / 64.f);
    float dv = o - mu;
    float sq = dv * dv;
#pragma unroll
    for (int d = 1; d < 64; d <<= 1) sq += __shfl_xor(sq, d, 64);
    float var = sq * (1.f / 64.f);
    float y = dv * rsqrtf(var + 1e-5f) * g[lane] + b[lane];
    hout[node * 64 + lane] = y;
}

// fallback pool (first, non-captured call only)
static void* g_pool = nullptr;
static size_t g_pool_sz = 0;

extern "C" void kernel_launch(void* const* d_in, const int* in_sizes, int n_in,
                              void* d_out, int out_size, void* d_ws, size_t ws_size,
                              hipStream_t stream) {
    const void* x    = d_in[0];             // [N,64]   f32 or bf16
    const int* ei    = (const int*)d_in[1]; // [2,E]
    const void* W_in = d_in[2];
    const void* b_in = d_in[3];
    const void* lw   = d_in[4];
    const void* lb   = d_in[5];
    const void* att  = d_in[6];
    const void* ob   = d_in[7];
    const void* lg   = d_in[8];
    const void* lbb  = d_in[9];

    const int n = in_sizes[0] / DD;      // 50000
    const int e = in_sizes[1] / 2;       // 800000
    const int* src = ei;
    const int* dst = ei + e;
    const int nscan = (n + 255) / 256;   // 196 blocks

    // ---- workspace sizing ----
    auto align256 = [](size_t v) { return (v + 255) & ~(size_t)255; };
    size_t need = 0;
    size_t off_h    = need; need += align256((size_t)n * DD * 4);
    size_t off_hp   = need; need += align256((size_t)n * DD * 4);
    size_t off_deg  = need; need += align256((size_t)n * 4);
    size_t off_offs = need; need += align256((size_t)(n + 1) * 4);
    size_t off_cur  = need; need += align256((size_t)n * 4);
    size_t off_csr  = need; need += align256((size_t)e * 4);
    size_t off_wts  = need; need += align256((size_t)26560 * 4);
    size_t off_flag = need; need += align256(4);
    size_t off_bsum = need; need += align256((size_t)nscan * 4);
    size_t off_bbas = need; need += align256((size_t)nscan * 4);

    char* ws;
    if (ws_size >= need) {
        ws = (char*)d_ws;
    } else {
        if (g_pool == nullptr || g_pool_sz < need) {
            hipMalloc(&g_pool, need);   // first call only; never during capture
            g_pool_sz = need;
        }
        ws = (char*)g_pool;
    }

    float* hbuf  = (float*)(ws + off_h);
    float* hpbuf = (float*)(ws + off_hp);
    int* deg     = (int*)(ws + off_deg);
    int* offs    = (int*)(ws + off_offs);
    int* cursor  = (int*)(ws + off_cur);
    int* csr     = (int*)(ws + off_csr);
    float* wts   = (float*)(ws + off_wts);
    int* flag    = (int*)(ws + off_flag);
    int* bsum    = (int*)(ws + off_bsum);
    int* bbase   = (int*)(ws + off_bbas);

    float* wW_in = wts;
    float* wb_in = wts + 4096;
    float* wlw   = wts + 4160;
    float* wlb   = wts + 24640;
    float* watt  = wts + 24960;
    float* wob   = wts + 25600;
    float* wlg   = wts + 25920;
    float* wlbb  = wts + 26240;

    // ---- dtype sniff + conversions ----
    sniff_k<<<1, 256, 0, stream>>>((const unsigned short*)x, flag);
    int nelem = n * DD;
    cvt_k<<<(nelem + 255) / 256, 256, 0, stream>>>(x, hpbuf, nelem, flag);
    cvtw_k<<<(26560 + 255) / 256, 256, 0, stream>>>(W_in, b_in, lw, lb, att, ob, lg, lbb,
                                                    wts, flag);

    // ---- CSR build ----
    hipMemsetAsync(deg, 0, (size_t)n * 4, stream);
    deg_k<<<(e + 255) / 256, 256, 0, stream>>>(dst, deg, e);
    scanA_k<<<nscan, 256, 0, stream>>>(deg, bsum, n);
    scanB_k<<<1, 256, 0, stream>>>(bsum, bbase, nscan, offs, n);
    scanC_k<<<nscan, 256, 0, stream>>>(deg, bbase, offs, cursor, n);
    scatter_k<<<(e + 255) / 256, 256, 0, stream>>>(src, dst, cursor, csr, e);

    // ---- input embedding: h = relu(x @ W_in + b_in) ----
    int gblocks = (n + 15) / 16;
    gemm64_k<<<gblocks, 256, 0, stream>>>(hpbuf, wW_in, wb_in, hbuf, n, 1);

    // ---- 5 GAT layers ----
    int ablocks = (n + 3) / 4;
    for (int l = 0; l < LL; ++l) {
        gemm64_k<<<gblocks, 256, 0, stream>>>(hbuf, wlw + (size_t)l * DD * DD,
                                              wlb + (size_t)l * DD, hpbuf, n, 0);
        gat_k<<<ablocks, 256, 0, stream>>>(hpbuf, offs, csr,
                                           watt + (size_t)l * HH * 2 * CC,
                                           wob + (size_t)l * DD,
                                           wlg + (size_t)l * DD,
                                           wlbb + (size_t)l * DD, hbuf, n);
    }

    // ---- store final h ----
    store_k<<<(nelem + 255) / 256, 256, 0, stream>>>(hbuf, d_out, nelem, flag);
}

// Round 5
// 705.530 us; speedup vs baseline: 1.1931x; 1.0307x over previous
//
#include <hip/hip_runtime.h>
#include <hip/hip_bf16.h>

#define DD 64
#define HH 8
#define CC 8
#define LL 5

// ---------------- dtype sniff ----------------
__global__ void sniff_k(const unsigned short* __restrict__ xb, int* __restrict__ flag) {
    __shared__ int any;
    if (threadIdx.x == 0) any = 0;
    __syncthreads();
    int bad = 0;
    for (int i = threadIdx.x; i < 4096; i += 256) {
        int e = (xb[i] >> 7) & 0xFF;
        if (e >= 134) bad = 1;
    }
    if (bad) atomicOr(&any, 1);
    __syncthreads();
    if (threadIdx.x == 0) *flag = any;  // 1 = float32 data, 0 = bf16 data
}

__global__ void cvt_k(const void* __restrict__ in, float* __restrict__ out, int n,
                      const int* __restrict__ flag) {
    int i = blockIdx.x * blockDim.x + threadIdx.x;
    if (i >= n) return;
    if (*flag) out[i] = ((const float*)in)[i];
    else       out[i] = (float)((const __hip_bfloat16*)in)[i];
}

__global__ void cvtw_k(const void* __restrict__ W_in, const void* __restrict__ b_in,
                       const void* __restrict__ lw, const void* __restrict__ lb,
                       const void* __restrict__ att, const void* __restrict__ ob,
                       const void* __restrict__ lg, const void* __restrict__ lbb,
                       float* __restrict__ wts, const int* __restrict__ flag) {
    int i = blockIdx.x * blockDim.x + threadIdx.x;
    if (i >= 26560) return;
    const void* p; int o;
    if      (i < 4096)  { p = W_in; o = i; }
    else if (i < 4160)  { p = b_in; o = i - 4096; }
    else if (i < 24640) { p = lw;   o = i - 4160; }
    else if (i < 24960) { p = lb;   o = i - 24640; }
    else if (i < 25600) { p = att;  o = i - 24960; }
    else if (i < 25920) { p = ob;   o = i - 25600; }
    else if (i < 26240) { p = lg;   o = i - 25920; }
    else                { p = lbb;  o = i - 26240; }
    wts[i] = (*flag) ? ((const float*)p)[o] : (float)((const __hip_bfloat16*)p)[o];
}

__global__ void store_k(const float* __restrict__ in, void* __restrict__ out, int n,
                        const int* __restrict__ flag) {
    int i = blockIdx.x * blockDim.x + threadIdx.x;
    if (i >= n) return;
    if (*flag) ((float*)out)[i] = in[i];
    else       ((__hip_bfloat16*)out)[i] = (__hip_bfloat16)in[i];
}

// ---------------- CSR build ----------------
__global__ void deg_k(const int* __restrict__ dst, int* __restrict__ deg, int e) {
    int i = blockIdx.x * blockDim.x + threadIdx.x;
    if (i < e) atomicAdd(&deg[dst[i]], 1);
}

__global__ void scanA_k(const int* __restrict__ deg, int* __restrict__ bsum, int n) {
    __shared__ int s[256];
    int i = blockIdx.x * 256 + threadIdx.x;
    s[threadIdx.x] = (i < n) ? deg[i] : 0;
    __syncthreads();
    for (int off = 128; off > 0; off >>= 1) {
        if (threadIdx.x < off) s[threadIdx.x] += s[threadIdx.x + off];
        __syncthreads();
    }
    if (threadIdx.x == 0) bsum[blockIdx.x] = s[0];
}

__global__ void scanB_k(const int* __restrict__ bsum, int* __restrict__ bbase, int nb,
                        int* __restrict__ offs, int n) {
    __shared__ int s[256];
    int t = threadIdx.x;
    s[t] = (t < nb) ? bsum[t] : 0;
    __syncthreads();
    for (int off = 1; off < 256; off <<= 1) {
        int v = (t >= off) ? s[t - off] : 0;
        __syncthreads();
        s[t] += v;
        __syncthreads();
    }
    if (t < nb) bbase[t] = (t == 0) ? 0 : s[t - 1];
    if (t == 255) offs[n] = s[255];
}

__global__ void scanC_k(const int* __restrict__ deg, const int* __restrict__ bbase,
                        int* __restrict__ offs, int* __restrict__ cursor, int n) {
    __shared__ int s[256];
    int t = threadIdx.x;
    int i = blockIdx.x * 256 + t;
    int v = (i < n) ? deg[i] : 0;
    s[t] = v;
    __syncthreads();
    for (int off = 1; off < 256; off <<= 1) {
        int u = (t >= off) ? s[t - off] : 0;
        __syncthreads();
        s[t] += u;
        __syncthreads();
    }
    if (i < n) {
        int excl = s[t] - v + bbase[blockIdx.x];
        offs[i] = excl;
        cursor[i] = excl;
    }
}

__global__ void scatter_k(const int* __restrict__ src, const int* __restrict__ dst,
                          int* __restrict__ cursor, int* __restrict__ csr, int e) {
    int i = blockIdx.x * blockDim.x + threadIdx.x;
    if (i < e) {
        int d = dst[i];
        int pos = atomicAdd(&cursor[d], 1);
        csr[pos] = src[i];
    }
}

// ---------------- GEMM: Out[n,64] = A[n,64] @ W[64,64] + bias, optional relu ----------------
__global__ void __launch_bounds__(256) gemm64_k(const float* __restrict__ A,
                                                const float* __restrict__ W,
                                                const float* __restrict__ bias,
                                                float* __restrict__ Out, int n, int relu) {
    __shared__ float Ws[64][64];
    __shared__ float As[16][64];
    int tid = threadIdx.x;
    for (int i = tid; i < 4096; i += 256) Ws[i >> 6][i & 63] = W[i];
    int rowbase = blockIdx.x * 16;
    for (int i = tid; i < 1024; i += 256) {
        int r = i >> 6, c = i & 63;
        int gr = rowbase + r;
        As[r][c] = (gr < n) ? A[gr * 64 + c] : 0.f;
    }
    __syncthreads();
    int c = tid & 63;
    int r0 = tid >> 6;
    float bcol = bias[c];
    for (int rr = 0; rr < 4; ++rr) {
        int r = r0 * 4 + rr;
        int gr = rowbase + r;
        if (gr >= n) break;
        float acc = 0.f;
#pragma unroll
        for (int k = 0; k < 64; ++k) acc += As[r][k] * Ws[k][c];
        acc += bcol;
        if (relu) acc = fmaxf(acc, 0.f);
        Out[gr * 64 + c] = acc;
    }
}

// ---------------- per-node attention scores ----------------
// bd[i][h] = sum_c hp[i][h*8+c]*att[h][c]   (dst score)
// ss[i][h] = sum_c hp[i][h*8+c]*att[h][8+c] (src score)
__global__ void score_k(const float* __restrict__ hp, const float* __restrict__ att,
                        float* __restrict__ bd, float* __restrict__ ss, int n8) {
    int t = blockIdx.x * blockDim.x + threadIdx.x;
    if (t >= n8) return;
    int i = t >> 3, h = t & 7;
    const float* row = hp + (size_t)i * 64 + h * 8;
    float d = 0.f, s = 0.f;
#pragma unroll
    for (int c = 0; c < 8; ++c) {
        float v = row[c];
        d += v * att[h * 16 + c];
        s += v * att[h * 16 + 8 + c];
    }
    bd[t] = d;
    ss[t] = s;
}

// ---------------- fused GAT layer (scores precomputed) ----------------
// one wave per node; lane = feature f = h*8+c
__global__ void __launch_bounds__(256) gat_k(const float* __restrict__ hp,   // [N,64]
                                             const int* __restrict__ offs,
                                             const int* __restrict__ csr,
                                             const float* __restrict__ bd,   // [N,8]
                                             const float* __restrict__ ss,   // [N,8]
                                             const float* __restrict__ ob,
                                             const float* __restrict__ g,
                                             const float* __restrict__ b,
                                             float* __restrict__ hout, int n) {
    int lane = threadIdx.x & 63;
    int wave = threadIdx.x >> 6;
    int node = blockIdx.x * 4 + wave;
    if (node >= n) return;
    int h = lane >> 3;

    float bh = bd[node * 8 + h];

    int rs = offs[node], re = offs[node + 1];
    float m = -INFINITY, s = 0.f, acc = 0.f;
    for (int base = rs; base < re; base += 64) {
        int cnt = min(64, re - base);
        int jv = (lane < cnt) ? csr[base + lane] : 0;
        for (int e = 0; e < cnt; ++e) {
            int j = __shfl(jv, e, 64);
            float xj = hp[(size_t)j * 64 + lane];
            float sj = ss[j * 8 + h];
            float alpha = bh + sj;
            alpha = (alpha > 0.f) ? alpha : 0.2f * alpha;  // leaky_relu 0.2
            float mn = fmaxf(m, alpha);
            float corr = __expf(m - mn);
            float ea = __expf(alpha - mn);
            s = s * corr + ea;
            acc = acc * corr + xj * ea;
            m = mn;
        }
    }

    float o = acc / (s + 1e-16f) + ob[lane];
    o = (o > 0.f) ? o : expm1f(o);  // ELU

    float sum = o;
#pragma unroll
    for (int d = 1; d < 64; d <<= 1) sum += __shfl_xor(sum, d, 64);
    float mu = sum * (1.f / 64.f);
    float dv = o - mu;
    float sq = dv * dv;
#pragma unroll
    for (int d = 1; d < 64; d <<= 1) sq += __shfl_xor(sq, d, 64);
    float var = sq * (1.f / 64.f);
    float y = dv * rsqrtf(var + 1e-5f) * g[lane] + b[lane];
    hout[(size_t)node * 64 + lane] = y;
}

// fallback pool (first, non-captured call only)
static void* g_pool = nullptr;
static size_t g_pool_sz = 0;

extern "C" void kernel_launch(void* const* d_in, const int* in_sizes, int n_in,
                              void* d_out, int out_size, void* d_ws, size_t ws_size,
                              hipStream_t stream) {
    const void* x    = d_in[0];
    const int* ei    = (const int*)d_in[1];
    const void* W_in = d_in[2];
    const void* b_in = d_in[3];
    const void* lw   = d_in[4];
    const void* lb   = d_in[5];
    const void* att  = d_in[6];
    const void* ob   = d_in[7];
    const void* lg   = d_in[8];
    const void* lbb  = d_in[9];

    const int n = in_sizes[0] / DD;      // 50000
    const int e = in_sizes[1] / 2;       // 800000
    const int* src = ei;
    const int* dst = ei + e;
    const int nscan = (n + 255) / 256;

    auto align256 = [](size_t v) { return (v + 255) & ~(size_t)255; };
    size_t need = 0;
    size_t off_h    = need; need += align256((size_t)n * DD * 4);
    size_t off_hp   = need; need += align256((size_t)n * DD * 4);
    size_t off_deg  = need; need += align256((size_t)n * 4);
    size_t off_offs = need; need += align256((size_t)(n + 1) * 4);
    size_t off_cur  = need; need += align256((size_t)n * 4);
    size_t off_csr  = need; need += align256((size_t)e * 4);
    size_t off_wts  = need; need += align256((size_t)26560 * 4);
    size_t off_flag = need; need += align256(4);
    size_t off_bsum = need; need += align256((size_t)nscan * 4);
    size_t off_bbas = need; need += align256((size_t)nscan * 4);
    size_t off_bd   = need; need += align256((size_t)n * 8 * 4);
    size_t off_ss   = need; need += align256((size_t)n * 8 * 4);

    char* ws;
    if (ws_size >= need) {
        ws = (char*)d_ws;
    } else {
        if (g_pool == nullptr || g_pool_sz < need) {
            hipMalloc(&g_pool, need);   // first call only; never during capture
            g_pool_sz = need;
        }
        ws = (char*)g_pool;
    }

    float* hbuf  = (float*)(ws + off_h);
    float* hpbuf = (float*)(ws + off_hp);
    int* deg     = (int*)(ws + off_deg);
    int* offs    = (int*)(ws + off_offs);
    int* cursor  = (int*)(ws + off_cur);
    int* csr     = (int*)(ws + off_csr);
    float* wts   = (float*)(ws + off_wts);
    int* flag    = (int*)(ws + off_flag);
    int* bsum    = (int*)(ws + off_bsum);
    int* bbase   = (int*)(ws + off_bbas);
    float* bd    = (float*)(ws + off_bd);
    float* ssb   = (float*)(ws + off_ss);

    float* wW_in = wts;
    float* wb_in = wts + 4096;
    float* wlw   = wts + 4160;
    float* wlb   = wts + 24640;
    float* watt  = wts + 24960;
    float* wob   = wts + 25600;
    float* wlg   = wts + 25920;
    float* wlbb  = wts + 26240;

    // ---- dtype sniff + conversions ----
    sniff_k<<<1, 256, 0, stream>>>((const unsigned short*)x, flag);
    int nelem = n * DD;
    cvt_k<<<(nelem + 255) / 256, 256, 0, stream>>>(x, hpbuf, nelem, flag);
    cvtw_k<<<(26560 + 255) / 256, 256, 0, stream>>>(W_in, b_in, lw, lb, att, ob, lg, lbb,
                                                    wts, flag);

    // ---- CSR build ----
    hipMemsetAsync(deg, 0, (size_t)n * 4, stream);
    deg_k<<<(e + 255) / 256, 256, 0, stream>>>(dst, deg, e);
    scanA_k<<<nscan, 256, 0, stream>>>(deg, bsum, n);
    scanB_k<<<1, 256, 0, stream>>>(bsum, bbase, nscan, offs, n);
    scanC_k<<<nscan, 256, 0, stream>>>(deg, bbase, offs, cursor, n);
    scatter_k<<<(e + 255) / 256, 256, 0, stream>>>(src, dst, cursor, csr, e);

    // ---- input embedding ----
    int gblocks = (n + 15) / 16;
    gemm64_k<<<gblocks, 256, 0, stream>>>(hpbuf, wW_in, wb_in, hbuf, n, 1);

    // ---- 5 GAT layers ----
    int ablocks = (n + 3) / 4;
    int n8 = n * 8;
    int sblocks = (n8 + 255) / 256;
    for (int l = 0; l < LL; ++l) {
        gemm64_k<<<gblocks, 256, 0, stream>>>(hbuf, wlw + (size_t)l * DD * DD,
                                              wlb + (size_t)l * DD, hpbuf, n, 0);
        score_k<<<sblocks, 256, 0, stream>>>(hpbuf, watt + (size_t)l * HH * 2 * CC,
                                             bd, ssb, n8);
        gat_k<<<ablocks, 256, 0, stream>>>(hpbuf, offs, csr, bd, ssb,
                                           wob + (size_t)l * DD,
                                           wlg + (size_t)l * DD,
                                           wlbb + (size_t)l * DD, hbuf, n);
    }

    // ---- store final h ----
    store_k<<<(nelem + 255) / 256, 256, 0, stream>>>(hbuf, d_out, nelem, flag);
}